// Round 2
// baseline (4726.801 us; speedup 1.0000x reference)
//
#include <hip/hip_runtime.h>
#include <math.h>

#define T_STEPS 4096
#define NB 16          // batch
#define NH 256         // hidden
#define BH (NB * NH)   // 4096 floats per time step
#define DT_STEP 0.1f

// ---------------- expm via Taylor series ----------------
// S = I + A
__global__ __launch_bounds__(1024) void k_init_S(const float* __restrict__ A,
                                                 float* __restrict__ S) {
    int idx = blockIdx.x * 1024 + threadIdx.x;
    int i = idx >> 8, j = idx & 255;
    S[idx] = A[idx] + (i == j ? 1.0f : 0.0f);
}

// Pnew = (Pprev @ A) * invk ; S += Pnew
__global__ __launch_bounds__(256) void k_expm_term(const float* __restrict__ Pprev,
                                                   const float* __restrict__ A,
                                                   float* __restrict__ Pnew,
                                                   float* __restrict__ S,
                                                   float invk) {
    __shared__ float prow[256];
    int i = blockIdx.x, j = threadIdx.x;
    prow[j] = Pprev[i * 256 + j];
    __syncthreads();
    float acc = 0.f;
#pragma unroll 8
    for (int m = 0; m < 256; ++m) acc = fmaf(prow[m], A[m * 256 + j], acc);
    float v = acc * invk;
    Pnew[i * 256 + j] = v;
    S[i * 256 + j] += v;
}

// ---------------- row-blocked GEMM: Out[r][o] = sum_k X[r][k]*Wm[o][k] + bias[o]
// K = 256, O = 256, 16 rows per block, 256 threads. Safe for X == Out
// (rows staged to LDS before any write).
__global__ __launch_bounds__(256) void k_gemm_rows(const float* __restrict__ X,
                                                   const float* __restrict__ Wm,
                                                   const float* __restrict__ bias,
                                                   float* __restrict__ Out) {
    __shared__ float4 xs4[16][64];
    const int tid = threadIdx.x;
    const long r0 = (long)blockIdx.x * 16;
    float* xs = (float*)xs4;
#pragma unroll
    for (int rr = 0; rr < 16; ++rr) xs[rr * 256 + tid] = X[(r0 + rr) * 256 + tid];
    __syncthreads();

    float acc[16];
#pragma unroll
    for (int rr = 0; rr < 16; ++rr) acc[rr] = 0.f;

    const float4* wrow = (const float4*)(Wm + tid * 256);
    for (int d4 = 0; d4 < 64; ++d4) {
        float4 w = wrow[d4];
#pragma unroll
        for (int rr = 0; rr < 16; ++rr) {
            float4 xv = xs4[rr][d4];
            acc[rr] = fmaf(w.x, xv.x, acc[rr]);
            acc[rr] = fmaf(w.y, xv.y, acc[rr]);
            acc[rr] = fmaf(w.z, xv.z, acc[rr]);
            acc[rr] = fmaf(w.w, xv.w, acc[rr]);
        }
    }
    float b = bias[tid];
#pragma unroll
    for (int rr = 0; rr < 16; ++rr) Out[(r0 + rr) * 256 + tid] = acc[rr] + b;
}

// ---------------- sequential scan: one block (CU) per batch element ----------------
// 512 threads = 8 waves. Thread (w=tid>>6, l=tid&63) owns output row
// i = (w<<5)|(l>>1) and K-half jc = l&1 (128 W floats in 32 float4 VGPRs).
// h double-buffered in LDS -> ONE barrier/step. Cross-half reduce is a single
// quad-perm __shfl_xor(p,1). h_i carried in-register. Fast tanh via __expf+rcp.
__global__ __launch_bounds__(512) void k_scan2(const float* __restrict__ u,
                                               const float* __restrict__ Wexp,
                                               float* __restrict__ hidden,
                                               float* __restrict__ hfin) {
    const int b = blockIdx.x;
    const int tid = threadIdx.x;
    const int w = tid >> 6;
    const int l = tid & 63;
    const int i = (w << 5) | (l >> 1);   // output row 0..255
    const int jc = l & 1;                // K-half 0/1

    __shared__ float4 hbuf[2][64];       // h[256] double-buffered

    // W[i][jc*128 .. +127] into 32 float4 registers
    float4 wv[32];
    const float4* wp = (const float4*)(Wexp + i * 256 + jc * 128);
#pragma unroll
    for (int k = 0; k < 32; ++k) wv[k] = wp[k];

    if (tid < 256) ((float*)hbuf[0])[tid] = 0.0f;

    const long ub = (long)b * NH + i;
    float u_cur = u[ub];
    float u_nxt = u[BH + ub];
    float hval = 0.0f;

    __syncthreads();

    for (int t = 0; t < T_STEPS; ++t) {
        float u_n2 = (t + 2 < T_STEPS) ? u[(long)(t + 2) * BH + ub] : 0.0f;
        const float4* hb = hbuf[t & 1];
        float* hw = (float*)hbuf[(t + 1) & 1];

        float a0 = 0.f, a1 = 0.f, a2 = 0.f, a3 = 0.f;
#pragma unroll
        for (int k = 0; k < 32; ++k) {
            float4 hv = hb[(jc << 5) + k];
            a0 = fmaf(wv[k].x, hv.x, a0);
            a1 = fmaf(wv[k].y, hv.y, a1);
            a2 = fmaf(wv[k].z, hv.z, a2);
            a3 = fmaf(wv[k].w, hv.w, a3);
        }
        float p = (a0 + a1) + (a2 + a3);
        p += __shfl_xor(p, 1, 64);       // sum the two K-halves (quad DPP)

        // hn = h + dt*tanh(u - y);  tanh(x) = (e^{2x}-1)/(e^{2x}+1)
        float xarg = u_cur - p;
        xarg = fminf(fmaxf(xarg, -9.0f), 9.0f);
        float E = __expf(2.0f * xarg);
        float th = (E - 1.0f) * __builtin_amdgcn_rcpf(E + 1.0f);
        hval = fmaf(DT_STEP, th, hval);

        if (jc == 0) {
            hw[i] = hval;                         // next h buffer
            hidden[(long)t * BH + ub] = hval;     // stage for output GEMM
        }
        u_cur = u_nxt;
        u_nxt = u_n2;
        __syncthreads();                          // next-buffer writes visible
    }
    if (jc == 0) hfin[ub] = hval;
}

extern "C" void kernel_launch(void* const* d_in, const int* in_sizes, int n_in,
                              void* d_out, int out_size, void* d_ws, size_t ws_size,
                              hipStream_t stream) {
    const float* x     = (const float*)d_in[0];  // [T,B,D]
    const float* U_w   = (const float*)d_in[1];  // [H,D]
    const float* U_b   = (const float*)d_in[2];  // [H]
    const float* W_log = (const float*)d_in[3];  // [H,H]
    const float* c_w   = (const float*)d_in[4];  // [O,H]
    const float* c_b   = (const float*)d_in[5];  // [O]

    float* out    = (float*)d_out;
    float* hidden = out;                          // stage hidden in d_out, then in-place GEMM
    float* hfin   = out + (long)T_STEPS * BH;     // second output chunk

    float* ws = (float*)d_ws;
    float* S  = ws;                // 65536 floats: Wexp accumulator
    float* Pa = ws + 65536;
    float* Pb = ws + 2 * 65536;
    float* u  = ws + 3 * 65536;    // 16,777,216 floats

    // Wexp = expm(W_log), Taylor K=9 (||W_log||_2 ~ 0.32 -> remainder ~1e-9)
    k_init_S<<<64, 1024, 0, stream>>>(W_log, S);
    const float* prev = W_log;
    float* cur = Pa;
    for (int k = 2; k <= 9; ++k) {
        k_expm_term<<<256, 256, 0, stream>>>(prev, W_log, cur, S, 1.0f / (float)k);
        prev = cur;
        cur = (cur == Pa) ? Pb : Pa;
    }

    // u = x @ U_w^T + U_b
    k_gemm_rows<<<4096, 256, 0, stream>>>(x, U_w, U_b, u);

    // sequential recurrence, hidden -> d_out
    k_scan2<<<NB, 512, 0, stream>>>(u, S, hidden, hfin);

    // out = hidden @ c_w^T + c_b, in place
    k_gemm_rows<<<4096, 256, 0, stream>>>(hidden, c_w, c_b, hidden);
}

// Round 3
// 2909.563 us; speedup vs baseline: 1.6246x; 1.6246x over previous
//
#include <hip/hip_runtime.h>
#include <math.h>

#define T_STEPS 4096
#define NB 16          // batch
#define NH 256         // hidden
#define BH (NB * NH)   // 4096 floats per time step
#define DT_STEP 0.1f

// ---------------- expm via Taylor series ----------------
__global__ __launch_bounds__(1024) void k_init_S(const float* __restrict__ A,
                                                 float* __restrict__ S) {
    int idx = blockIdx.x * 1024 + threadIdx.x;
    int i = idx >> 8, j = idx & 255;
    S[idx] = A[idx] + (i == j ? 1.0f : 0.0f);
}

__global__ __launch_bounds__(256) void k_expm_term(const float* __restrict__ Pprev,
                                                   const float* __restrict__ A,
                                                   float* __restrict__ Pnew,
                                                   float* __restrict__ S,
                                                   float invk) {
    __shared__ float prow[256];
    int i = blockIdx.x, j = threadIdx.x;
    prow[j] = Pprev[i * 256 + j];
    __syncthreads();
    float acc = 0.f;
#pragma unroll 8
    for (int m = 0; m < 256; ++m) acc = fmaf(prow[m], A[m * 256 + j], acc);
    float v = acc * invk;
    Pnew[i * 256 + j] = v;
    S[i * 256 + j] += v;
}

// ---------------- row-blocked GEMM (unchanged, works) ----------------
__global__ __launch_bounds__(256) void k_gemm_rows(const float* __restrict__ X,
                                                   const float* __restrict__ Wm,
                                                   const float* __restrict__ bias,
                                                   float* __restrict__ Out) {
    __shared__ float4 xs4[16][64];
    const int tid = threadIdx.x;
    const long r0 = (long)blockIdx.x * 16;
    float* xs = (float*)xs4;
#pragma unroll
    for (int rr = 0; rr < 16; ++rr) xs[rr * 256 + tid] = X[(r0 + rr) * 256 + tid];
    __syncthreads();

    float acc[16];
#pragma unroll
    for (int rr = 0; rr < 16; ++rr) acc[rr] = 0.f;

    const float4* wrow = (const float4*)(Wm + tid * 256);
    for (int d4 = 0; d4 < 64; ++d4) {
        float4 w = wrow[d4];
#pragma unroll
        for (int rr = 0; rr < 16; ++rr) {
            float4 xv = xs4[rr][d4];
            acc[rr] = fmaf(w.x, xv.x, acc[rr]);
            acc[rr] = fmaf(w.y, xv.y, acc[rr]);
            acc[rr] = fmaf(w.z, xv.z, acc[rr]);
            acc[rr] = fmaf(w.w, xv.w, acc[rr]);
        }
    }
    float b = bias[tid];
#pragma unroll
    for (int rr = 0; rr < 16; ++rr) Out[(r0 + rr) * 256 + tid] = acc[rr] + b;
}

// DPP butterfly add: x + x[lane ^ k] for k in {1,2,8} via quad_perm / row_ror:8
template <int CTRL>
__device__ __forceinline__ float dpp_add(float x) {
    int yi = __builtin_amdgcn_mov_dpp(__float_as_int(x), CTRL, 0xF, 0xF, true);
    return x + __int_as_float(yi);
}

// ---------------- sequential scan: one block (CU) per batch element ----------------
// 512 threads = 8 waves. Wave w owns rows 32w..32w+31.
// Lane l: K-chunk c = bits{0,1,3} of l (32 floats), row-quad q = bits{2,4,5}.
// Each thread: 4 rows x 32-float chunk of W = 128 VGPRs, pinned via asm.
// h double-buffered in LDS with bank-rotation swizzle (8 addrs -> 32 banks,
// 8-way broadcast, conflict-free). 8 ds_read_b128 per wave per step.
// K-reduce = DPP xor1/xor2/xor8 (pure VALU). One barrier/step.
__global__ __launch_bounds__(512, 2) void k_scan3(const float* __restrict__ u,
                                                  const float* Wexp,   // no restrict: forbid remat
                                                  float* hidden,       // no restrict: forbid remat
                                                  float* __restrict__ hfin) {
    const int b = blockIdx.x;
    const int tid = threadIdx.x;
    const int w = tid >> 6;
    const int l = tid & 63;
    const int c = (l & 3) | ((l & 8) >> 1);          // chunk 0..7  (lane bits 0,1,3)
    const int q = ((l >> 2) & 1) | ((l >> 3) & 6);   // row-quad 0..7 (lane bits 2,4,5)
    const int i0 = (w << 5) | (q << 2);              // first of this thread's 4 rows
    const bool wr = ((l & 8) == 0);                  // writer lanes (c < 4)
    const int cc = c & 3;                            // component owned by writer lane

    __shared__ float4 hbuf[2][64];                   // h[256] double-buffered, swizzled

    // W[i0+j][32c .. 32c+31] -> 32 float4 = 128 VGPRs
    float4 wreg[4][8];
#pragma unroll
    for (int j = 0; j < 4; ++j) {
        const float4* wp = (const float4*)(Wexp + (i0 + j) * 256 + (c << 5));
#pragma unroll
        for (int k4 = 0; k4 < 8; ++k4) wreg[j][k4] = wp[k4];
    }
    // pin: opaque asm def -> cannot be rematerialized from memory
#pragma unroll
    for (int j = 0; j < 4; ++j)
#pragma unroll
        for (int k4 = 0; k4 < 8; ++k4)
            asm volatile("" : "+v"(wreg[j][k4].x), "+v"(wreg[j][k4].y),
                              "+v"(wreg[j][k4].z), "+v"(wreg[j][k4].w));

    // swizzled byte offsets: float4 f=8c+k4 stored at 128c + 16*((k4+c)&7)
    int haddr[8];
#pragma unroll
    for (int k4 = 0; k4 < 8; ++k4) haddr[k4] = (c << 7) | (((k4 + c) & 7) << 4);
    const int waddr = (w << 7) | (((q + w) & 7) << 4) | (cc << 2);

    ((float*)hbuf)[tid] = 0.0f;                      // zero both buffers (512 floats)

    const float* up = u + b * NH + i0 + cc;
    float* hp = hidden + b * NH + i0 + cc;

    float u_cur = 0.f, u_nxt = 0.f, hval = 0.f;
    if (wr) {
        u_cur = up[0];
        u_nxt = up[BH];
    }
    __syncthreads();

    const char* rb = (const char*)hbuf;
    char* wb = (char*)hbuf;

#define SCAN_STEP(ROFF, WOFF, T)                                               \
    {                                                                          \
        float u_n2 = 0.f;                                                      \
        if (wr && (T) + 2 < T_STEPS) u_n2 = up[(size_t)((T) + 2) * BH];        \
        float4 a0 = {0, 0, 0, 0}, a1 = {0, 0, 0, 0};                           \
        float4 a2 = {0, 0, 0, 0}, a3 = {0, 0, 0, 0};                           \
        _Pragma("unroll")                                                      \
        for (int k4 = 0; k4 < 8; ++k4) {                                       \
            float4 hv = *(const float4*)(rb + (ROFF) + haddr[k4]);             \
            a0.x = fmaf(wreg[0][k4].x, hv.x, a0.x);                            \
            a0.y = fmaf(wreg[0][k4].y, hv.y, a0.y);                            \
            a0.z = fmaf(wreg[0][k4].z, hv.z, a0.z);                            \
            a0.w = fmaf(wreg[0][k4].w, hv.w, a0.w);                            \
            a1.x = fmaf(wreg[1][k4].x, hv.x, a1.x);                            \
            a1.y = fmaf(wreg[1][k4].y, hv.y, a1.y);                            \
            a1.z = fmaf(wreg[1][k4].z, hv.z, a1.z);                            \
            a1.w = fmaf(wreg[1][k4].w, hv.w, a1.w);                            \
            a2.x = fmaf(wreg[2][k4].x, hv.x, a2.x);                            \
            a2.y = fmaf(wreg[2][k4].y, hv.y, a2.y);                            \
            a2.z = fmaf(wreg[2][k4].z, hv.z, a2.z);                            \
            a2.w = fmaf(wreg[2][k4].w, hv.w, a2.w);                            \
            a3.x = fmaf(wreg[3][k4].x, hv.x, a3.x);                            \
            a3.y = fmaf(wreg[3][k4].y, hv.y, a3.y);                            \
            a3.z = fmaf(wreg[3][k4].z, hv.z, a3.z);                            \
            a3.w = fmaf(wreg[3][k4].w, hv.w, a3.w);                            \
        }                                                                      \
        float p0 = (a0.x + a0.y) + (a0.z + a0.w);                              \
        float p1 = (a1.x + a1.y) + (a1.z + a1.w);                              \
        float p2 = (a2.x + a2.y) + (a2.z + a2.w);                              \
        float p3 = (a3.x + a3.y) + (a3.z + a3.w);                              \
        p0 = dpp_add<0xB1>(p0); p0 = dpp_add<0x4E>(p0); p0 = dpp_add<0x128>(p0);\
        p1 = dpp_add<0xB1>(p1); p1 = dpp_add<0x4E>(p1); p1 = dpp_add<0x128>(p1);\
        p2 = dpp_add<0xB1>(p2); p2 = dpp_add<0x4E>(p2); p2 = dpp_add<0x128>(p2);\
        p3 = dpp_add<0xB1>(p3); p3 = dpp_add<0x4E>(p3); p3 = dpp_add<0x128>(p3);\
        float y = (c & 2) ? ((c & 1) ? p3 : p2) : ((c & 1) ? p1 : p0);         \
        if (wr) {                                                              \
            float xa = u_cur - y;                                              \
            xa = fminf(fmaxf(xa, -9.0f), 9.0f);                                \
            float E = __expf(2.0f * xa);                                       \
            float th = (E - 1.0f) * __builtin_amdgcn_rcpf(E + 1.0f);           \
            hval = fmaf(DT_STEP, th, hval);                                    \
            *(float*)(wb + (WOFF) + waddr) = hval;                             \
            hp[(size_t)(T) * BH] = hval;                                       \
        }                                                                      \
        u_cur = u_nxt; u_nxt = u_n2;                                           \
        __syncthreads();                                                       \
    }

    for (int t = 0; t < T_STEPS; t += 2) {
        SCAN_STEP(0, 1024, t)
        SCAN_STEP(1024, 0, t + 1)
    }
#undef SCAN_STEP

    if (wr) hfin[b * NH + i0 + cc] = hval;
}

extern "C" void kernel_launch(void* const* d_in, const int* in_sizes, int n_in,
                              void* d_out, int out_size, void* d_ws, size_t ws_size,
                              hipStream_t stream) {
    const float* x     = (const float*)d_in[0];  // [T,B,D]
    const float* U_w   = (const float*)d_in[1];  // [H,D]
    const float* U_b   = (const float*)d_in[2];  // [H]
    const float* W_log = (const float*)d_in[3];  // [H,H]
    const float* c_w   = (const float*)d_in[4];  // [O,H]
    const float* c_b   = (const float*)d_in[5];  // [O]

    float* out    = (float*)d_out;
    float* hidden = out;                          // stage hidden in d_out, then in-place GEMM
    float* hfin   = out + (long)T_STEPS * BH;     // second output chunk

    float* ws = (float*)d_ws;
    float* S  = ws;                // 65536 floats: Wexp accumulator
    float* Pa = ws + 65536;
    float* Pb = ws + 2 * 65536;
    float* u  = ws + 3 * 65536;    // 16,777,216 floats

    // Wexp = expm(W_log), Taylor K=9 (||W_log||_2 ~ 0.32 -> remainder ~1e-9)
    k_init_S<<<64, 1024, 0, stream>>>(W_log, S);
    const float* prev = W_log;
    float* cur = Pa;
    for (int k = 2; k <= 9; ++k) {
        k_expm_term<<<256, 256, 0, stream>>>(prev, W_log, cur, S, 1.0f / (float)k);
        prev = cur;
        cur = (cur == Pa) ? Pb : Pa;
    }

    // u = x @ U_w^T + U_b
    k_gemm_rows<<<4096, 256, 0, stream>>>(x, U_w, U_b, u);

    // sequential recurrence, hidden -> d_out
    k_scan3<<<NB, 512, 0, stream>>>(u, S, hidden, hfin);

    // out = hidden @ c_w^T + c_b, in place
    k_gemm_rows<<<4096, 256, 0, stream>>>(hidden, c_w, c_b, hidden);
}